// Round 5
// baseline (1234.877 us; speedup 1.0000x reference)
//
#include <hip/hip_runtime.h>
#include <hip/hip_bf16.h>

typedef __hip_bfloat16 bf16;
using short8  = __attribute__((ext_vector_type(8))) short;
using float4_ = __attribute__((ext_vector_type(4))) float;

#define B_    4
#define C_    192
#define NN    16384   // 128*128
#define HEADS 4
#define CHD   48
#define TOT   1152    // 576 qkv + 192 q_mut + 384 kv_mut

__device__ __forceinline__ float b2f(bf16 v) { return __bfloat162float(v); }

// ---------------------------------------------------------------------------
// kprep_w: concat+cast 1x1 weights -> Wb[1152][192] bf16.
// ---------------------------------------------------------------------------
__global__ __launch_bounds__(256) void kprep_w(
    const float* __restrict__ qkv_w, const float* __restrict__ qm_w,
    const float* __restrict__ kvm_w, bf16* __restrict__ Wb)
{
    int i = blockIdx.x * 256 + threadIdx.x;
    if (i >= TOT * C_) return;
    int r = i / C_, c = i % C_;
    float v = (r < 576) ? qkv_w[r * C_ + c]
            : (r < 768) ? qm_w[(r - 576) * C_ + c]
                        : kvm_w[(r - 768) * C_ + c];
    Wb[i] = __float2bfloat16(v);
}

// ---------------------------------------------------------------------------
// kprep_x: per-batch transpose+cast x / x_hidden -> Xt[2][16384][192] bf16.
// ---------------------------------------------------------------------------
__global__ __launch_bounds__(256) void kprep_x(
    const float* __restrict__ x, const float* __restrict__ xh,
    int b, bf16* __restrict__ Xt)
{
    const int src = blockIdx.z;
    const float* in = (src == 0 ? x : xh) + (size_t)b * C_ * NN;
    bf16* outp = Xt + (size_t)src * NN * C_;
    const int n0 = blockIdx.x * 32, c0 = blockIdx.y * 32;
    __shared__ float t[32][33];
    const int tid = threadIdx.x;
    const int ln = tid & 31, lc = tid >> 5;
    #pragma unroll
    for (int it = 0; it < 4; ++it)
        t[lc + it * 8][ln] = in[(size_t)(c0 + lc + it * 8) * NN + n0 + ln];
    __syncthreads();
    const int lc2 = tid & 31, ln2 = tid >> 5;
    #pragma unroll
    for (int it = 0; it < 4; ++it)
        outp[(size_t)(n0 + ln2 + it * 8) * C_ + c0 + lc2] =
            __float2bfloat16(t[lc2][ln2 + it * 8]);
}

// ---------------------------------------------------------------------------
// kgemm: per-batch Y[1152][16384] = Wb[1152][192] x X[192][16384], bf16 MFMA.
// ---------------------------------------------------------------------------
__global__ __launch_bounds__(256) void kgemm(
    const bf16* __restrict__ Wb, const bf16* __restrict__ Xt,
    bf16* __restrict__ Y)
{
    const int nt0 = blockIdx.x * 128;
    const int mt0 = blockIdx.y * 64;
    const int tid = threadIdx.x;
    const bf16* Xs = Xt + (mt0 >= 768 ? (size_t)NN * C_ : 0);

    __shared__ short sA[64][72];
    __shared__ short sB[128][72];

    const int wave = tid >> 6, lane = tid & 63;
    const int mw = (wave & 1) * 32, nw = (wave >> 1) * 64;
    const int lm = lane & 15, lq = lane >> 4;

    float4_ acc[2][4];
    #pragma unroll
    for (int i = 0; i < 2; ++i)
        #pragma unroll
        for (int j = 0; j < 4; ++j)
            acc[i][j] = (float4_){0.f, 0.f, 0.f, 0.f};

    for (int kc = 0; kc < 192; kc += 64) {
        __syncthreads();
        {
            int r = tid >> 3, c8 = (tid & 7) * 8;
            #pragma unroll
            for (int it = 0; it < 2; ++it, r += 32)
                *(short8*)&sA[r][c8] =
                    *(const short8*)&Wb[(size_t)(mt0 + r) * C_ + kc + c8];
        }
        {
            int r = tid >> 3, c8 = (tid & 7) * 8;
            #pragma unroll
            for (int it = 0; it < 4; ++it, r += 32)
                *(short8*)&sB[r][c8] =
                    *(const short8*)&Xs[(size_t)(nt0 + r) * C_ + kc + c8];
        }
        __syncthreads();
        #pragma unroll
        for (int kk = 0; kk < 64; kk += 32) {
            short8 af[2], bfr[4];
            const int ko = kk + lq * 8;
            #pragma unroll
            for (int i = 0; i < 2; ++i)
                af[i] = *(const short8*)&sA[mw + i * 16 + lm][ko];
            #pragma unroll
            for (int j = 0; j < 4; ++j)
                bfr[j] = *(const short8*)&sB[nw + j * 16 + lm][ko];
            #pragma unroll
            for (int i = 0; i < 2; ++i)
                #pragma unroll
                for (int j = 0; j < 4; ++j)
                    acc[i][j] = __builtin_amdgcn_mfma_f32_16x16x32_bf16(
                        af[i], bfr[j], acc[i][j], 0, 0, 0);
        }
    }
    #pragma unroll
    for (int i = 0; i < 2; ++i)
        #pragma unroll
        for (int j = 0; j < 4; ++j) {
            const int n = nt0 + nw + j * 16 + lm;
            #pragma unroll
            for (int r = 0; r < 4; ++r) {
                const int m = mt0 + mw + i * 16 + lq * 4 + r;
                Y[(size_t)m * NN + n] = __float2bfloat16(acc[i][j][r]);
            }
        }
}

// ---------------------------------------------------------------------------
// kdw: per-batch depthwise 3x3 Y -> QT[b], fused L2-norm sumsq accumulation
// (classes q/k/q_mut/k_mut) into nrmsq[b][cls][192] via atomicAdd.
// grid (64 tiles, 1152 ch), block 256; all threads of a block share one ch.
// ---------------------------------------------------------------------------
__global__ __launch_bounds__(256) void kdw(
    const bf16* __restrict__ Y,
    const float* __restrict__ qkv_dw, const float* __restrict__ qm_dw,
    const float* __restrict__ kvm_dw, int b, bf16* __restrict__ QT,
    float* __restrict__ nrmsq)
{
    const int ch = blockIdx.y;
    const int tile = blockIdx.x;
    const int x0 = (tile & 3) * 32, y0 = (tile >> 2) * 8;
    const int tid = threadIdx.x;
    const int xx = x0 + (tid & 31), yy = y0 + (tid >> 5);
    const float* dwp = (ch < 576) ? qkv_dw + (size_t)ch * 9
                     : (ch < 768) ? qm_dw + (size_t)(ch - 576) * 9
                                  : kvm_dw + (size_t)(ch - 768) * 9;
    const bf16* Yc = Y + (size_t)ch * NN;
    float s = 0.f;
    #pragma unroll
    for (int dy = -1; dy <= 1; ++dy)
        #pragma unroll
        for (int dx = -1; dx <= 1; ++dx) {
            const int gy = yy + dy, gx = xx + dx;
            const float v = (gy >= 0 && gy < 128 && gx >= 0 && gx < 128)
                          ? b2f(Yc[gy * 128 + gx]) : 0.f;
            s += dwp[(dy + 1) * 3 + (dx + 1)] * v;
        }
    QT[((size_t)b * TOT + ch) * NN + yy * 128 + xx] = __float2bfloat16(s);

    // fused sum-of-squares for norm classes
    int cls = -1, ci = 0;
    if (ch < 192)                    { cls = 0; ci = ch; }
    else if (ch < 384)               { cls = 1; ci = ch - 192; }
    else if (ch >= 576 && ch < 768)  { cls = 2; ci = ch - 576; }
    else if (ch >= 768 && ch < 960)  { cls = 3; ci = ch - 768; }
    if (cls >= 0) {
        float sq = s * s;
        #pragma unroll
        for (int off = 32; off > 0; off >>= 1) sq += __shfl_down(sq, off);
        __shared__ float red[4];
        if ((tid & 63) == 0) red[tid >> 6] = sq;
        __syncthreads();
        if (tid == 0)
            atomicAdd(&nrmsq[(b * 4 + cls) * 192 + ci],
                      red[0] + red[1] + red[2] + red[3]);
    }
}

// ---------------------------------------------------------------------------
// ktv: transpose v/v_mut from QT -> Vt[b][16384][384] bf16
// (cols 0..191 = v channels, 192..383 = v_mut channels).
// grid (512 n-tiles of 32, 6 c-tiles of 32, 8 = b*2+src), block 256.
// ---------------------------------------------------------------------------
__global__ __launch_bounds__(256) void ktv(
    const bf16* __restrict__ QT, bf16* __restrict__ Vt)
{
    const int bs = blockIdx.z;
    const int b = bs >> 1, src = bs & 1;
    const int n0 = blockIdx.x * 32, c0 = blockIdx.y * 32;
    const int chbase = (src == 0) ? 384 : 960;
    const int colbase = (src == 0) ? 0 : 192;
    __shared__ short t[32][33];
    const int tid = threadIdx.x;
    const int ln = tid & 31, lc = tid >> 5;
    const bf16* qb = QT + ((size_t)b * TOT + chbase + c0) * NN;
    #pragma unroll
    for (int it = 0; it < 4; ++it)
        t[lc + it * 8][ln] =
            *(const short*)&qb[(size_t)(lc + it * 8) * NN + n0 + ln];
    __syncthreads();
    const int lc2 = tid & 31, ln2 = tid >> 5;
    bf16* vb = Vt + (size_t)b * NN * 384;
    #pragma unroll
    for (int it = 0; it < 4; ++it)
        *(short*)&vb[(size_t)(n0 + ln2 + it * 8) * 384 + colbase + c0 + lc2] =
            t[lc2][ln2 + it * 8];
}

// ---------------------------------------------------------------------------
// K3: unnormalized Gram matrices G[t][b][h][48][48].
// ---------------------------------------------------------------------------
__global__ __launch_bounds__(256) void k3_gram(
    const bf16* __restrict__ QT, float* __restrict__ G)
{
    const int chunk = blockIdx.x;
    const int t = blockIdx.y >> 2, h = blockIdx.y & 3;
    const int b = blockIdx.z;
    const int qch = (t == 0 ? 0 : 576) + h * CHD;
    const int kch = (t == 0 ? 192 : 768) + h * CHD;
    const bf16* qp = QT + ((size_t)b * TOT + qch) * NN;
    const bf16* kp = QT + ((size_t)b * TOT + kch) * NN;

    __shared__ float sQ[48][65];
    __shared__ float sK[48][65];

    const int tid = threadIdx.x;
    const int c0 = (tid >> 4) * 3, d0 = (tid & 15) * 3;
    float acc[3][3] = {};
    const int n0 = chunk * 2048;

    for (int nt = 0; nt < 2048; nt += 64) {
        __syncthreads();
        for (int i = tid; i < 48 * 64; i += 256) {
            int c = i >> 6, j = i & 63;
            sQ[c][j] = b2f(qp[c * NN + n0 + nt + j]);
            sK[c][j] = b2f(kp[c * NN + n0 + nt + j]);
        }
        __syncthreads();
        for (int j = 0; j < 64; ++j) {
            float qv[3], kv[3];
            #pragma unroll
            for (int i = 0; i < 3; ++i) { qv[i] = sQ[c0 + i][j]; kv[i] = sK[d0 + i][j]; }
            #pragma unroll
            for (int i = 0; i < 3; ++i)
                #pragma unroll
                for (int jj = 0; jj < 3; ++jj) acc[i][jj] += qv[i] * kv[jj];
        }
    }
    float* Gp = G + (((size_t)t * 4 + b) * 4 + h) * 48 * 48;
    #pragma unroll
    for (int i = 0; i < 3; ++i)
        #pragma unroll
        for (int jj = 0; jj < 3; ++jj)
            atomicAdd(&Gp[(c0 + i) * 48 + d0 + jj], acc[i][jj]);
}

// ---------------------------------------------------------------------------
// K4: softmax(G * temp / (|q||k|)) then fold proj -> Mb bf16 [b][o][384]
// (cols 0..191 = M1 (v path), 192..383 = M2 (v_mut path)).
// nrmsq holds sum-of-squares (sqrt here). grid (4 h, 2 t, 4 b).
// ---------------------------------------------------------------------------
__global__ __launch_bounds__(256) void k4_softmax_m(
    const float* __restrict__ G, const float* __restrict__ nrmsq,
    const float* __restrict__ proj_w, const float* __restrict__ tq,
    const float* __restrict__ tm, bf16* __restrict__ Mb)
{
    const int h = blockIdx.x, t = blockIdx.y, b = blockIdx.z;
    const float* Gp = G + (((size_t)t * 4 + b) * 4 + h) * 2304;
    __shared__ float sA[48][49];
    const int tid = threadIdx.x;

    if (tid < 48) {
        const int c = tid;
        const int clsq = (t == 0) ? 0 : 2, clsk = (t == 0) ? 1 : 3;
        const float nq =
            fmaxf(sqrtf(fmaxf(nrmsq[(b * 4 + clsq) * 192 + h * 48 + c], 0.f)), 1e-12f);
        const float tmp = (t == 0 ? tq[h] : tm[h]);
        float L[48];
        float mx = -1e30f;
        for (int d = 0; d < 48; ++d) {
            float nk =
                fmaxf(sqrtf(fmaxf(nrmsq[(b * 4 + clsk) * 192 + h * 48 + d], 0.f)), 1e-12f);
            L[d] = Gp[c * 48 + d] * tmp / (nq * nk);
            mx = fmaxf(mx, L[d]);
        }
        float sum = 0.f;
        for (int d = 0; d < 48; ++d) { L[d] = expf(L[d] - mx); sum += L[d]; }
        const float inv = 1.f / sum;
        for (int d = 0; d < 48; ++d) sA[c][d] = L[d] * inv;
    }
    __syncthreads();

    for (int idx = tid; idx < 192 * 48; idx += 256) {
        const int o = idx / 48, d = idx % 48;
        const float* pw = proj_w + o * 384 + t * 192 + h * 48;
        float s = 0.f;
        for (int c = 0; c < 48; ++c) s += pw[c] * sA[c][d];
        Mb[((size_t)b * 192 + o) * 384 + t * 192 + h * 48 + d] = __float2bfloat16(s);
    }
}

// ---------------------------------------------------------------------------
// k5_mfma: out[b][192][16384] = Mb[b][192][384] x Vt[b][16384][384]^T (MFMA).
// grid (128 n-tiles, 3 m-tiles of 64, 4 b), block 256 (4 waves, 32m x 64n).
// A frags loaded direct from global (Mb is 147 KB/batch, L2-resident).
// ---------------------------------------------------------------------------
__global__ __launch_bounds__(256) void k5_mfma(
    const bf16* __restrict__ Mb, const bf16* __restrict__ Vt,
    float* __restrict__ out)
{
    const int nt0 = blockIdx.x * 128;
    const int mt0 = blockIdx.y * 64;
    const int b   = blockIdx.z;
    const int tid = threadIdx.x;

    __shared__ short sB[128][72];

    const int wave = tid >> 6, lane = tid & 63;
    const int mw = (wave & 1) * 32, nw = (wave >> 1) * 64;
    const int lm = lane & 15, lq = lane >> 4;

    const bf16* Vb = Vt + (size_t)b * NN * 384;
    const bf16* Mp = Mb + (size_t)b * 192 * 384;

    float4_ acc[2][4];
    #pragma unroll
    for (int i = 0; i < 2; ++i)
        #pragma unroll
        for (int j = 0; j < 4; ++j)
            acc[i][j] = (float4_){0.f, 0.f, 0.f, 0.f};

    for (int kc = 0; kc < 384; kc += 64) {
        __syncthreads();
        {
            int r = tid >> 3, c8 = (tid & 7) * 8;
            #pragma unroll
            for (int it = 0; it < 4; ++it, r += 32)
                *(short8*)&sB[r][c8] =
                    *(const short8*)&Vb[(size_t)(nt0 + r) * 384 + kc + c8];
        }
        __syncthreads();
        #pragma unroll
        for (int kk = 0; kk < 64; kk += 32) {
            short8 af[2], bfr[4];
            const int ko = kk + lq * 8;
            #pragma unroll
            for (int i = 0; i < 2; ++i)
                af[i] = *(const short8*)
                    &Mp[(size_t)(mt0 + mw + i * 16 + lm) * 384 + kc + ko];
            #pragma unroll
            for (int j = 0; j < 4; ++j)
                bfr[j] = *(const short8*)&sB[nw + j * 16 + lm][ko];
            #pragma unroll
            for (int i = 0; i < 2; ++i)
                #pragma unroll
                for (int j = 0; j < 4; ++j)
                    acc[i][j] = __builtin_amdgcn_mfma_f32_16x16x32_bf16(
                        af[i], bfr[j], acc[i][j], 0, 0, 0);
        }
    }
    #pragma unroll
    for (int i = 0; i < 2; ++i)
        #pragma unroll
        for (int j = 0; j < 4; ++j) {
            const int n = nt0 + nw + j * 16 + lm;
            #pragma unroll
            for (int r = 0; r < 4; ++r) {
                const int m = mt0 + mw + i * 16 + lq * 4 + r;
                out[((size_t)b * C_ + m) * NN + n] = acc[i][j][r];
            }
        }
}

// ---------------------------------------------------------------------------
extern "C" void kernel_launch(void* const* d_in, const int* in_sizes, int n_in,
                              void* d_out, int out_size, void* d_ws, size_t ws_size,
                              hipStream_t stream)
{
    const float* x     = (const float*)d_in[0];
    const float* xh    = (const float*)d_in[1];
    const float* qkvw  = (const float*)d_in[2];
    const float* qkvdw = (const float*)d_in[3];
    const float* qmw   = (const float*)d_in[4];
    const float* qmdw  = (const float*)d_in[5];
    const float* kvmw  = (const float*)d_in[6];
    const float* kvmdw = (const float*)d_in[7];
    const float* projw = (const float*)d_in[8];
    const float* tq    = (const float*)d_in[9];
    const float* tm    = (const float*)d_in[10];
    float* out = (float*)d_out;

    char* ws = (char*)d_ws;
    size_t off = 0;
    bf16*  QT = (bf16*)(ws + off);  off += (size_t)B_ * TOT * NN * 2;   // 151.0 MB
    // Y (37.75 MB) + Xt (12.58 MB) live only during the batch loop;
    // Vt (4*16384*384*2 = 50.33 MB = Y+Xt exactly) overlays them afterwards.
    bf16*  Y  = (bf16*)(ws + off);
    bf16*  Vt = (bf16*)(ws + off);  off += (size_t)TOT * NN * 2;
    bf16*  Xt = (bf16*)(ws + off);  off += (size_t)2 * NN * C_ * 2;
    bf16*  Wb = (bf16*)(ws + off);  off += (size_t)TOT * C_ * 2;
    float* nrm = (float*)(ws + off); off += (size_t)B_ * 4 * 192 * 4;
    float* G   = (float*)(ws + off); off += (size_t)2 * B_ * HEADS * 48 * 48 * 4;
    bf16*  Mb  = (bf16*)(ws + off);  off += (size_t)B_ * 192 * 384 * 2;

    hipMemsetAsync(G, 0, (size_t)2 * B_ * HEADS * 48 * 48 * 4, stream);
    hipMemsetAsync(nrm, 0, (size_t)B_ * 4 * 192 * 4, stream);

    kprep_w<<<dim3((TOT * C_ + 255) / 256), 256, 0, stream>>>(qkvw, qmw, kvmw, Wb);

    for (int b = 0; b < B_; ++b) {
        kprep_x<<<dim3(512, 6, 2), 256, 0, stream>>>(x, xh, b, Xt);
        kgemm  <<<dim3(128, 18), 256, 0, stream>>>(Wb, Xt, Y);
        kdw    <<<dim3(64, 1152), 256, 0, stream>>>(Y, qkvdw, qmdw, kvmdw, b, QT, nrm);
    }

    ktv         <<<dim3(512, 6, 8), 256, 0, stream>>>(QT, Vt);
    k3_gram     <<<dim3(8, 8, B_), 256, 0, stream>>>(QT, G);
    k4_softmax_m<<<dim3(4, 2, B_), 256, 0, stream>>>(G, nrm, projw, tq, tm, Mb);
    k5_mfma     <<<dim3(128, 3, B_), 256, 0, stream>>>(Mb, Vt, out);
}

// Round 6
// 1021.422 us; speedup vs baseline: 1.2090x; 1.2090x over previous
//
#include <hip/hip_runtime.h>
#include <hip/hip_bf16.h>

typedef __hip_bfloat16 bf16;
using short8  = __attribute__((ext_vector_type(8))) short;
using float4_ = __attribute__((ext_vector_type(4))) float;

#define B_    4
#define C_    192
#define NN    16384   // 128*128
#define HEADS 4
#define CHD   48
#define TOT   1152    // 576 qkv + 192 q_mut + 384 kv_mut

__device__ __forceinline__ float b2f(bf16 v) { return __bfloat162float(v); }

// ---------------------------------------------------------------------------
// kprep_w: concat+cast 1x1 weights -> Wb[1152][192] bf16.
// ---------------------------------------------------------------------------
__global__ __launch_bounds__(256) void kprep_w(
    const float* __restrict__ qkv_w, const float* __restrict__ qm_w,
    const float* __restrict__ kvm_w, bf16* __restrict__ Wb)
{
    int i = blockIdx.x * 256 + threadIdx.x;
    if (i >= TOT * C_) return;
    int r = i / C_, c = i % C_;
    float v = (r < 576) ? qkv_w[r * C_ + c]
            : (r < 768) ? qm_w[(r - 576) * C_ + c]
                        : kvm_w[(r - 768) * C_ + c];
    Wb[i] = __float2bfloat16(v);
}

// ---------------------------------------------------------------------------
// kprep_x: per-batch transpose+cast x / x_hidden -> Xt[2][16384][192] bf16.
// ---------------------------------------------------------------------------
__global__ __launch_bounds__(256) void kprep_x(
    const float* __restrict__ x, const float* __restrict__ xh,
    int b, bf16* __restrict__ Xt)
{
    const int src = blockIdx.z;
    const float* in = (src == 0 ? x : xh) + (size_t)b * C_ * NN;
    bf16* outp = Xt + (size_t)src * NN * C_;
    const int n0 = blockIdx.x * 32, c0 = blockIdx.y * 32;
    __shared__ float t[32][33];
    const int tid = threadIdx.x;
    const int ln = tid & 31, lc = tid >> 5;
    #pragma unroll
    for (int it = 0; it < 4; ++it)
        t[lc + it * 8][ln] = in[(size_t)(c0 + lc + it * 8) * NN + n0 + ln];
    __syncthreads();
    const int lc2 = tid & 31, ln2 = tid >> 5;
    #pragma unroll
    for (int it = 0; it < 4; ++it)
        outp[(size_t)(n0 + ln2 + it * 8) * C_ + c0 + lc2] =
            __float2bfloat16(t[lc2][ln2 + it * 8]);
}

// ---------------------------------------------------------------------------
// kgemm: per-batch Y[1152][16384] = Wb[1152][192] x X[192][16384], bf16 MFMA.
// ---------------------------------------------------------------------------
__global__ __launch_bounds__(256) void kgemm(
    const bf16* __restrict__ Wb, const bf16* __restrict__ Xt,
    bf16* __restrict__ Y)
{
    const int nt0 = blockIdx.x * 128;
    const int mt0 = blockIdx.y * 64;
    const int tid = threadIdx.x;
    const bf16* Xs = Xt + (mt0 >= 768 ? (size_t)NN * C_ : 0);

    __shared__ short sA[64][72];
    __shared__ short sB[128][72];

    const int wave = tid >> 6, lane = tid & 63;
    const int mw = (wave & 1) * 32, nw = (wave >> 1) * 64;
    const int lm = lane & 15, lq = lane >> 4;

    float4_ acc[2][4];
    #pragma unroll
    for (int i = 0; i < 2; ++i)
        #pragma unroll
        for (int j = 0; j < 4; ++j)
            acc[i][j] = (float4_){0.f, 0.f, 0.f, 0.f};

    for (int kc = 0; kc < 192; kc += 64) {
        __syncthreads();
        {
            int r = tid >> 3, c8 = (tid & 7) * 8;
            #pragma unroll
            for (int it = 0; it < 2; ++it, r += 32)
                *(short8*)&sA[r][c8] =
                    *(const short8*)&Wb[(size_t)(mt0 + r) * C_ + kc + c8];
        }
        {
            int r = tid >> 3, c8 = (tid & 7) * 8;
            #pragma unroll
            for (int it = 0; it < 4; ++it, r += 32)
                *(short8*)&sB[r][c8] =
                    *(const short8*)&Xs[(size_t)(nt0 + r) * C_ + kc + c8];
        }
        __syncthreads();
        #pragma unroll
        for (int kk = 0; kk < 64; kk += 32) {
            short8 af[2], bfr[4];
            const int ko = kk + lq * 8;
            #pragma unroll
            for (int i = 0; i < 2; ++i)
                af[i] = *(const short8*)&sA[mw + i * 16 + lm][ko];
            #pragma unroll
            for (int j = 0; j < 4; ++j)
                bfr[j] = *(const short8*)&sB[nw + j * 16 + lm][ko];
            #pragma unroll
            for (int i = 0; i < 2; ++i)
                #pragma unroll
                for (int j = 0; j < 4; ++j)
                    acc[i][j] = __builtin_amdgcn_mfma_f32_16x16x32_bf16(
                        af[i], bfr[j], acc[i][j], 0, 0, 0);
        }
    }
    #pragma unroll
    for (int i = 0; i < 2; ++i)
        #pragma unroll
        for (int j = 0; j < 4; ++j) {
            const int n = nt0 + nw + j * 16 + lm;
            #pragma unroll
            for (int r = 0; r < 4; ++r) {
                const int m = mt0 + mw + i * 16 + lq * 4 + r;
                Y[(size_t)m * NN + n] = __float2bfloat16(acc[i][j][r]);
            }
        }
}

// ---------------------------------------------------------------------------
// kdw: per-batch depthwise 3x3 Y -> QT[b], fused L2-norm sumsq accumulation
// into nrmsq[b][cls][192] via atomicAdd.
// ---------------------------------------------------------------------------
__global__ __launch_bounds__(256) void kdw(
    const bf16* __restrict__ Y,
    const float* __restrict__ qkv_dw, const float* __restrict__ qm_dw,
    const float* __restrict__ kvm_dw, int b, bf16* __restrict__ QT,
    float* __restrict__ nrmsq)
{
    const int ch = blockIdx.y;
    const int tile = blockIdx.x;
    const int x0 = (tile & 3) * 32, y0 = (tile >> 2) * 8;
    const int tid = threadIdx.x;
    const int xx = x0 + (tid & 31), yy = y0 + (tid >> 5);
    const float* dwp = (ch < 576) ? qkv_dw + (size_t)ch * 9
                     : (ch < 768) ? qm_dw + (size_t)(ch - 576) * 9
                                  : kvm_dw + (size_t)(ch - 768) * 9;
    const bf16* Yc = Y + (size_t)ch * NN;
    float s = 0.f;
    #pragma unroll
    for (int dy = -1; dy <= 1; ++dy)
        #pragma unroll
        for (int dx = -1; dx <= 1; ++dx) {
            const int gy = yy + dy, gx = xx + dx;
            const float v = (gy >= 0 && gy < 128 && gx >= 0 && gx < 128)
                          ? b2f(Yc[gy * 128 + gx]) : 0.f;
            s += dwp[(dy + 1) * 3 + (dx + 1)] * v;
        }
    QT[((size_t)b * TOT + ch) * NN + yy * 128 + xx] = __float2bfloat16(s);

    int cls = -1, ci = 0;
    if (ch < 192)                    { cls = 0; ci = ch; }
    else if (ch < 384)               { cls = 1; ci = ch - 192; }
    else if (ch >= 576 && ch < 768)  { cls = 2; ci = ch - 576; }
    else if (ch >= 768 && ch < 960)  { cls = 3; ci = ch - 768; }
    if (cls >= 0) {
        float sq = s * s;
        #pragma unroll
        for (int off = 32; off > 0; off >>= 1) sq += __shfl_down(sq, off);
        __shared__ float red[4];
        if ((tid & 63) == 0) red[tid >> 6] = sq;
        __syncthreads();
        if (tid == 0)
            atomicAdd(&nrmsq[(b * 4 + cls) * 192 + ci],
                      red[0] + red[1] + red[2] + red[3]);
    }
}

// ---------------------------------------------------------------------------
// ktv: transpose v/v_mut from QT -> Vt[b][16384][384] bf16.
// ---------------------------------------------------------------------------
__global__ __launch_bounds__(256) void ktv(
    const bf16* __restrict__ QT, bf16* __restrict__ Vt)
{
    const int bs = blockIdx.z;
    const int b = bs >> 1, src = bs & 1;
    const int n0 = blockIdx.x * 32, c0 = blockIdx.y * 32;
    const int chbase = (src == 0) ? 384 : 960;
    const int colbase = (src == 0) ? 0 : 192;
    __shared__ short t[32][33];
    const int tid = threadIdx.x;
    const int ln = tid & 31, lc = tid >> 5;
    const bf16* qb = QT + ((size_t)b * TOT + chbase + c0) * NN;
    #pragma unroll
    for (int it = 0; it < 4; ++it)
        t[lc + it * 8][ln] =
            *(const short*)&qb[(size_t)(lc + it * 8) * NN + n0 + ln];
    __syncthreads();
    const int lc2 = tid & 31, ln2 = tid >> 5;
    bf16* vb = Vt + (size_t)b * NN * 384;
    #pragma unroll
    for (int it = 0; it < 4; ++it)
        *(short*)&vb[(size_t)(n0 + ln2 + it * 8) * 384 + colbase + c0 + lc2] =
            t[lc2][ln2 + it * 8];
}

// ---------------------------------------------------------------------------
// k3_mfma: Gram partials via MFMA, operands direct from global (k = n is
// already contiguous in QT). grid (32 n-chunks of 512, 8 = t*4+h, 4 b),
// block 256 = 4 waves; wave w covers k-range [chunk*512 + w*128, +128).
// Gpart[gidx][chunk][48*48], gidx = (t*4+b)*4+h.
// ---------------------------------------------------------------------------
__global__ __launch_bounds__(256) void k3_mfma(
    const bf16* __restrict__ QT, float* __restrict__ Gpart)
{
    const int chunk = blockIdx.x;
    const int t = blockIdx.y >> 2, h = blockIdx.y & 3;
    const int b = blockIdx.z;
    const int qch = (t == 0 ? 0 : 576) + h * CHD;
    const int kch = (t == 0 ? 192 : 768) + h * CHD;
    const bf16* qp = QT + ((size_t)b * TOT + qch) * NN;
    const bf16* kp = QT + ((size_t)b * TOT + kch) * NN;

    const int tid = threadIdx.x;
    const int wave = tid >> 6, lane = tid & 63;
    const int lm = lane & 15, lq = lane >> 4;
    const int n0 = chunk * 512 + wave * 128;

    float4_ acc[3][3];
    #pragma unroll
    for (int i = 0; i < 3; ++i)
        #pragma unroll
        for (int j = 0; j < 3; ++j)
            acc[i][j] = (float4_){0.f, 0.f, 0.f, 0.f};

    #pragma unroll
    for (int kk = 0; kk < 128; kk += 32) {
        short8 af[3], bfr[3];
        const int ko = n0 + kk + lq * 8;
        #pragma unroll
        for (int i = 0; i < 3; ++i)
            af[i] = *(const short8*)&qp[(size_t)(i * 16 + lm) * NN + ko];
        #pragma unroll
        for (int j = 0; j < 3; ++j)
            bfr[j] = *(const short8*)&kp[(size_t)(j * 16 + lm) * NN + ko];
        #pragma unroll
        for (int i = 0; i < 3; ++i)
            #pragma unroll
            for (int j = 0; j < 3; ++j)
                acc[i][j] = __builtin_amdgcn_mfma_f32_16x16x32_bf16(
                    af[i], bfr[j], acc[i][j], 0, 0, 0);
    }

    // per-wave partials -> LDS (row stride 49 to spread banks), sum 4 waves
    __shared__ float sW[4][48 * 49];
    #pragma unroll
    for (int i = 0; i < 3; ++i)
        #pragma unroll
        for (int j = 0; j < 3; ++j)
            #pragma unroll
            for (int r = 0; r < 4; ++r)
                sW[wave][(i * 16 + lq * 4 + r) * 49 + j * 16 + lm] = acc[i][j][r];
    __syncthreads();

    const int gidx = ((t * 4 + b) * 4 + h);
    float* Gp = Gpart + ((size_t)gidx * 32 + chunk) * 2304;
    for (int idx = tid; idx < 2304; idx += 256) {
        const int c = idx / 48, d = idx % 48;
        Gp[idx] = sW[0][c * 49 + d] + sW[1][c * 49 + d]
                + sW[2][c * 49 + d] + sW[3][c * 49 + d];
    }
}

// ---------------------------------------------------------------------------
// kred: G[gidx][2304] = sum over 32 chunks of Gpart[gidx][chunk][2304].
// ---------------------------------------------------------------------------
__global__ __launch_bounds__(256) void kred(
    const float* __restrict__ Gpart, float* __restrict__ G)
{
    const int idx = blockIdx.x * 256 + threadIdx.x;
    if (idx >= 32 * 2304) return;
    const int g = idx / 2304, i = idx % 2304;
    const float* p = Gpart + (size_t)g * 32 * 2304 + i;
    float s = 0.f;
    #pragma unroll
    for (int ch = 0; ch < 32; ++ch) s += p[(size_t)ch * 2304];
    G[(size_t)g * 2304 + i] = s;
}

// ---------------------------------------------------------------------------
// K4: softmax(G * temp / (|q||k|)) then fold proj -> Mb bf16 [b][o][384].
// ---------------------------------------------------------------------------
__global__ __launch_bounds__(256) void k4_softmax_m(
    const float* __restrict__ G, const float* __restrict__ nrmsq,
    const float* __restrict__ proj_w, const float* __restrict__ tq,
    const float* __restrict__ tm, bf16* __restrict__ Mb)
{
    const int h = blockIdx.x, t = blockIdx.y, b = blockIdx.z;
    const float* Gp = G + (((size_t)t * 4 + b) * 4 + h) * 2304;
    __shared__ float sA[48][49];
    const int tid = threadIdx.x;

    if (tid < 48) {
        const int c = tid;
        const int clsq = (t == 0) ? 0 : 2, clsk = (t == 0) ? 1 : 3;
        const float nq =
            fmaxf(sqrtf(fmaxf(nrmsq[(b * 4 + clsq) * 192 + h * 48 + c], 0.f)), 1e-12f);
        const float tmp = (t == 0 ? tq[h] : tm[h]);
        float L[48];
        float mx = -1e30f;
        for (int d = 0; d < 48; ++d) {
            float nk =
                fmaxf(sqrtf(fmaxf(nrmsq[(b * 4 + clsk) * 192 + h * 48 + d], 0.f)), 1e-12f);
            L[d] = Gp[c * 48 + d] * tmp / (nq * nk);
            mx = fmaxf(mx, L[d]);
        }
        float sum = 0.f;
        for (int d = 0; d < 48; ++d) { L[d] = expf(L[d] - mx); sum += L[d]; }
        const float inv = 1.f / sum;
        for (int d = 0; d < 48; ++d) sA[c][d] = L[d] * inv;
    }
    __syncthreads();

    for (int idx = tid; idx < 192 * 48; idx += 256) {
        const int o = idx / 48, d = idx % 48;
        const float* pw = proj_w + o * 384 + t * 192 + h * 48;
        float s = 0.f;
        for (int c = 0; c < 48; ++c) s += pw[c] * sA[c][d];
        Mb[((size_t)b * 192 + o) * 384 + t * 192 + h * 48 + d] = __float2bfloat16(s);
    }
}

// ---------------------------------------------------------------------------
// k5_mfma: out[b][192][16384] = Mb[b][192][384] x Vt[b][16384][384]^T (MFMA).
// ---------------------------------------------------------------------------
__global__ __launch_bounds__(256) void k5_mfma(
    const bf16* __restrict__ Mb, const bf16* __restrict__ Vt,
    float* __restrict__ out)
{
    const int nt0 = blockIdx.x * 128;
    const int mt0 = blockIdx.y * 64;
    const int b   = blockIdx.z;
    const int tid = threadIdx.x;

    __shared__ short sB[128][72];

    const int wave = tid >> 6, lane = tid & 63;
    const int mw = (wave & 1) * 32, nw = (wave >> 1) * 64;
    const int lm = lane & 15, lq = lane >> 4;

    const bf16* Vb = Vt + (size_t)b * NN * 384;
    const bf16* Mp = Mb + (size_t)b * 192 * 384;

    float4_ acc[2][4];
    #pragma unroll
    for (int i = 0; i < 2; ++i)
        #pragma unroll
        for (int j = 0; j < 4; ++j)
            acc[i][j] = (float4_){0.f, 0.f, 0.f, 0.f};

    for (int kc = 0; kc < 384; kc += 64) {
        __syncthreads();
        {
            int r = tid >> 3, c8 = (tid & 7) * 8;
            #pragma unroll
            for (int it = 0; it < 4; ++it, r += 32)
                *(short8*)&sB[r][c8] =
                    *(const short8*)&Vb[(size_t)(nt0 + r) * 384 + kc + c8];
        }
        __syncthreads();
        #pragma unroll
        for (int kk = 0; kk < 64; kk += 32) {
            short8 af[2], bfr[4];
            const int ko = kk + lq * 8;
            #pragma unroll
            for (int i = 0; i < 2; ++i)
                af[i] = *(const short8*)
                    &Mp[(size_t)(mt0 + mw + i * 16 + lm) * 384 + kc + ko];
            #pragma unroll
            for (int j = 0; j < 4; ++j)
                bfr[j] = *(const short8*)&sB[nw + j * 16 + lm][ko];
            #pragma unroll
            for (int i = 0; i < 2; ++i)
                #pragma unroll
                for (int j = 0; j < 4; ++j)
                    acc[i][j] = __builtin_amdgcn_mfma_f32_16x16x32_bf16(
                        af[i], bfr[j], acc[i][j], 0, 0, 0);
        }
    }
    #pragma unroll
    for (int i = 0; i < 2; ++i)
        #pragma unroll
        for (int j = 0; j < 4; ++j) {
            const int n = nt0 + nw + j * 16 + lm;
            #pragma unroll
            for (int r = 0; r < 4; ++r) {
                const int m = mt0 + mw + i * 16 + lq * 4 + r;
                out[((size_t)b * C_ + m) * NN + n] = acc[i][j][r];
            }
        }
}

// ---------------------------------------------------------------------------
extern "C" void kernel_launch(void* const* d_in, const int* in_sizes, int n_in,
                              void* d_out, int out_size, void* d_ws, size_t ws_size,
                              hipStream_t stream)
{
    const float* x     = (const float*)d_in[0];
    const float* xh    = (const float*)d_in[1];
    const float* qkvw  = (const float*)d_in[2];
    const float* qkvdw = (const float*)d_in[3];
    const float* qmw   = (const float*)d_in[4];
    const float* qmdw  = (const float*)d_in[5];
    const float* kvmw  = (const float*)d_in[6];
    const float* kvmdw = (const float*)d_in[7];
    const float* projw = (const float*)d_in[8];
    const float* tq    = (const float*)d_in[9];
    const float* tm    = (const float*)d_in[10];
    float* out = (float*)d_out;

    char* ws = (char*)d_ws;
    size_t off = 0;
    bf16*  QT = (bf16*)(ws + off);  off += (size_t)B_ * TOT * NN * 2;   // 151.0 MB
    bf16*  Y  = (bf16*)(ws + off);                                      // batch-loop only
    bf16*  Vt = (bf16*)(ws + off);  off += (size_t)TOT * NN * 2;        // overlays Y(+Xt)
    bf16*  Xt = (bf16*)(ws + off);  off += (size_t)2 * NN * C_ * 2;
    bf16*  Wb = (bf16*)(ws + off);  off += (size_t)TOT * C_ * 2;
    float* nrm = (float*)(ws + off); off += (size_t)B_ * 4 * 192 * 4;
    float* G   = (float*)(ws + off); off += (size_t)2 * B_ * HEADS * 48 * 48 * 4;
    bf16*  Mb  = (bf16*)(ws + off);  off += (size_t)B_ * 192 * 384 * 2;
    float* Gpart = (float*)(ws + off); off += (size_t)32 * 32 * 2304 * 4;  // 9.4 MB

    hipMemsetAsync(nrm, 0, (size_t)B_ * 4 * 192 * 4, stream);

    kprep_w<<<dim3((TOT * C_ + 255) / 256), 256, 0, stream>>>(qkvw, qmw, kvmw, Wb);

    for (int b = 0; b < B_; ++b) {
        kprep_x<<<dim3(512, 6, 2), 256, 0, stream>>>(x, xh, b, Xt);
        kgemm  <<<dim3(128, 18), 256, 0, stream>>>(Wb, Xt, Y);
        kdw    <<<dim3(64, 1152), 256, 0, stream>>>(Y, qkvdw, qmdw, kvmdw, b, QT, nrm);
    }

    ktv         <<<dim3(512, 6, 8), 256, 0, stream>>>(QT, Vt);
    k3_mfma     <<<dim3(32, 8, B_), 256, 0, stream>>>(QT, Gpart);
    kred        <<<dim3((32 * 2304 + 255) / 256), 256, 0, stream>>>(Gpart, G);
    k4_softmax_m<<<dim3(4, 2, B_), 256, 0, stream>>>(G, nrm, projw, tq, tm, Mb);
    k5_mfma     <<<dim3(128, 3, B_), 256, 0, stream>>>(Mb, Vt, out);
}

// Round 7
// 422.664 us; speedup vs baseline: 2.9217x; 2.4166x over previous
//
#include <hip/hip_runtime.h>
#include <hip/hip_bf16.h>

typedef __hip_bfloat16 bf16;
using short8  = __attribute__((ext_vector_type(8))) short;
using float4_ = __attribute__((ext_vector_type(4))) float;

#define B_    4
#define C_    192
#define NN    16384   // 128*128
#define HEADS 4
#define CHD   48
#define TOT   1152    // 576 qkv + 192 q_mut + 384 kv_mut

__device__ __forceinline__ float b2f(bf16 v) { return __bfloat162float(v); }
__device__ __forceinline__ float s2f(short s) {
    return __uint_as_float(((unsigned)(unsigned short)s) << 16);
}

// ---------------------------------------------------------------------------
// kprep_w: concat+cast 1x1 weights -> Wb[1152][192] bf16.
// ---------------------------------------------------------------------------
__global__ __launch_bounds__(256) void kprep_w(
    const float* __restrict__ qkv_w, const float* __restrict__ qm_w,
    const float* __restrict__ kvm_w, bf16* __restrict__ Wb)
{
    int i = blockIdx.x * 256 + threadIdx.x;
    if (i >= TOT * C_) return;
    int r = i / C_, c = i % C_;
    float v = (r < 576) ? qkv_w[r * C_ + c]
            : (r < 768) ? qm_w[(r - 576) * C_ + c]
                        : kvm_w[(r - 768) * C_ + c];
    Wb[i] = __float2bfloat16(v);
}

// ---------------------------------------------------------------------------
// kprep_x: per-batch transpose+cast x / x_hidden -> Xt[2][16384][192] bf16.
// ---------------------------------------------------------------------------
__global__ __launch_bounds__(256) void kprep_x(
    const float* __restrict__ x, const float* __restrict__ xh,
    int b, bf16* __restrict__ Xt)
{
    const int src = blockIdx.z;
    const float* in = (src == 0 ? x : xh) + (size_t)b * C_ * NN;
    bf16* outp = Xt + (size_t)src * NN * C_;
    const int n0 = blockIdx.x * 32, c0 = blockIdx.y * 32;
    __shared__ float t[32][33];
    const int tid = threadIdx.x;
    const int ln = tid & 31, lc = tid >> 5;
    #pragma unroll
    for (int it = 0; it < 4; ++it)
        t[lc + it * 8][ln] = in[(size_t)(c0 + lc + it * 8) * NN + n0 + ln];
    __syncthreads();
    const int lc2 = tid & 31, ln2 = tid >> 5;
    #pragma unroll
    for (int it = 0; it < 4; ++it)
        outp[(size_t)(n0 + ln2 + it * 8) * C_ + c0 + lc2] =
            __float2bfloat16(t[lc2][ln2 + it * 8]);
}

// ---------------------------------------------------------------------------
// kgemm: per-batch Y[1152][16384] = Wb[1152][192] x X[192][16384], bf16 MFMA.
// ---------------------------------------------------------------------------
__global__ __launch_bounds__(256) void kgemm(
    const bf16* __restrict__ Wb, const bf16* __restrict__ Xt,
    bf16* __restrict__ Y)
{
    const int nt0 = blockIdx.x * 128;
    const int mt0 = blockIdx.y * 64;
    const int tid = threadIdx.x;
    const bf16* Xs = Xt + (mt0 >= 768 ? (size_t)NN * C_ : 0);

    __shared__ short sA[64][72];
    __shared__ short sB[128][72];

    const int wave = tid >> 6, lane = tid & 63;
    const int mw = (wave & 1) * 32, nw = (wave >> 1) * 64;
    const int lm = lane & 15, lq = lane >> 4;

    float4_ acc[2][4];
    #pragma unroll
    for (int i = 0; i < 2; ++i)
        #pragma unroll
        for (int j = 0; j < 4; ++j)
            acc[i][j] = (float4_){0.f, 0.f, 0.f, 0.f};

    for (int kc = 0; kc < 192; kc += 64) {
        __syncthreads();
        {
            int r = tid >> 3, c8 = (tid & 7) * 8;
            #pragma unroll
            for (int it = 0; it < 2; ++it, r += 32)
                *(short8*)&sA[r][c8] =
                    *(const short8*)&Wb[(size_t)(mt0 + r) * C_ + kc + c8];
        }
        {
            int r = tid >> 3, c8 = (tid & 7) * 8;
            #pragma unroll
            for (int it = 0; it < 4; ++it, r += 32)
                *(short8*)&sB[r][c8] =
                    *(const short8*)&Xs[(size_t)(nt0 + r) * C_ + kc + c8];
        }
        __syncthreads();
        #pragma unroll
        for (int kk = 0; kk < 64; kk += 32) {
            short8 af[2], bfr[4];
            const int ko = kk + lq * 8;
            #pragma unroll
            for (int i = 0; i < 2; ++i)
                af[i] = *(const short8*)&sA[mw + i * 16 + lm][ko];
            #pragma unroll
            for (int j = 0; j < 4; ++j)
                bfr[j] = *(const short8*)&sB[nw + j * 16 + lm][ko];
            #pragma unroll
            for (int i = 0; i < 2; ++i)
                #pragma unroll
                for (int j = 0; j < 4; ++j)
                    acc[i][j] = __builtin_amdgcn_mfma_f32_16x16x32_bf16(
                        af[i], bfr[j], acc[i][j], 0, 0, 0);
        }
    }
    #pragma unroll
    for (int i = 0; i < 2; ++i)
        #pragma unroll
        for (int j = 0; j < 4; ++j) {
            const int n = nt0 + nw + j * 16 + lm;
            #pragma unroll
            for (int r = 0; r < 4; ++r) {
                const int m = mt0 + mw + i * 16 + lq * 4 + r;
                Y[(size_t)m * NN + n] = __float2bfloat16(acc[i][j][r]);
            }
        }
}

// ---------------------------------------------------------------------------
// kdw: per-batch depthwise 3x3 Y -> QT[b], register-resident row-sliding.
// grid (1152 ch, 2 half-images), block 256 = 16x16; thread = 8-wide x 4-row
// strip. Per output row: 1 short8 + 2 scalar halo loads (new row only),
// 72 FMA, one 16B packed store. Fused L2-norm sumsq -> nrmsq atomicAdd.
// ---------------------------------------------------------------------------
__device__ __forceinline__ void kdw_load_row(
    float* r, const bf16* __restrict__ Yc, int row, int x0)
{
    if (row < 0 || row > 127) {
        #pragma unroll
        for (int i = 0; i < 10; ++i) r[i] = 0.f;
        return;
    }
    const bf16* p = Yc + row * 128 + x0;
    short8 v = *(const short8*)p;
    #pragma unroll
    for (int i = 0; i < 8; ++i) r[i + 1] = s2f(v[i]);
    r[0] = (x0 > 0)   ? b2f(p[-1]) : 0.f;
    r[9] = (x0 < 120) ? b2f(p[8])  : 0.f;
}

__global__ __launch_bounds__(256) void kdw(
    const bf16* __restrict__ Y,
    const float* __restrict__ qkv_dw, const float* __restrict__ qm_dw,
    const float* __restrict__ kvm_dw, int b, bf16* __restrict__ QT,
    float* __restrict__ nrmsq)
{
    const int ch  = blockIdx.x;
    const int tid = threadIdx.x;
    const int tx = tid & 15, ty = tid >> 4;
    const int x0 = tx * 8;
    const int y0 = blockIdx.y * 64 + ty * 4;

    const float* dwp = (ch < 576) ? qkv_dw + (size_t)ch * 9
                     : (ch < 768) ? qm_dw + (size_t)(ch - 576) * 9
                                  : kvm_dw + (size_t)(ch - 768) * 9;
    float w[9];
    #pragma unroll
    for (int i = 0; i < 9; ++i) w[i] = dwp[i];

    const bf16* Yc = Y + (size_t)ch * NN;
    bf16* qout = QT + ((size_t)b * TOT + ch) * NN;

    float r0[10], r1[10], r2[10];
    kdw_load_row(r0, Yc, y0 - 1, x0);
    kdw_load_row(r1, Yc, y0,     x0);

    float ssq = 0.f;
    #pragma unroll
    for (int yy = 0; yy < 4; ++yy) {
        kdw_load_row(r2, Yc, y0 + yy + 1, x0);
        short8 sv;
        #pragma unroll
        for (int xx = 0; xx < 8; ++xx) {
            float s = w[0] * r0[xx] + w[1] * r0[xx + 1] + w[2] * r0[xx + 2]
                    + w[3] * r1[xx] + w[4] * r1[xx + 1] + w[5] * r1[xx + 2]
                    + w[6] * r2[xx] + w[7] * r2[xx + 1] + w[8] * r2[xx + 2];
            ssq += s * s;
            bf16 h = __float2bfloat16(s);
            sv[xx] = *reinterpret_cast<short*>(&h);
        }
        *(short8*)&qout[(size_t)(y0 + yy) * 128 + x0] = sv;
        #pragma unroll
        for (int i = 0; i < 10; ++i) { r0[i] = r1[i]; r1[i] = r2[i]; }
    }

    // fused sum-of-squares for norm classes q/k/q_mut/k_mut
    int cls = -1, ci = 0;
    if (ch < 192)                    { cls = 0; ci = ch; }
    else if (ch < 384)               { cls = 1; ci = ch - 192; }
    else if (ch >= 576 && ch < 768)  { cls = 2; ci = ch - 576; }
    else if (ch >= 768 && ch < 960)  { cls = 3; ci = ch - 768; }
    if (cls >= 0) {
        #pragma unroll
        for (int off = 32; off > 0; off >>= 1) ssq += __shfl_down(ssq, off);
        __shared__ float red[4];
        if ((tid & 63) == 0) red[tid >> 6] = ssq;
        __syncthreads();
        if (tid == 0)
            atomicAdd(&nrmsq[(b * 4 + cls) * 192 + ci],
                      red[0] + red[1] + red[2] + red[3]);
    }
}

// ---------------------------------------------------------------------------
// ktv: transpose v/v_mut from QT -> Vt[b][16384][384] bf16.
// ---------------------------------------------------------------------------
__global__ __launch_bounds__(256) void ktv(
    const bf16* __restrict__ QT, bf16* __restrict__ Vt)
{
    const int bs = blockIdx.z;
    const int b = bs >> 1, src = bs & 1;
    const int n0 = blockIdx.x * 32, c0 = blockIdx.y * 32;
    const int chbase = (src == 0) ? 384 : 960;
    const int colbase = (src == 0) ? 0 : 192;
    __shared__ short t[32][33];
    const int tid = threadIdx.x;
    const int ln = tid & 31, lc = tid >> 5;
    const bf16* qb = QT + ((size_t)b * TOT + chbase + c0) * NN;
    #pragma unroll
    for (int it = 0; it < 4; ++it)
        t[lc + it * 8][ln] =
            *(const short*)&qb[(size_t)(lc + it * 8) * NN + n0 + ln];
    __syncthreads();
    const int lc2 = tid & 31, ln2 = tid >> 5;
    bf16* vb = Vt + (size_t)b * NN * 384;
    #pragma unroll
    for (int it = 0; it < 4; ++it)
        *(short*)&vb[(size_t)(n0 + ln2 + it * 8) * 384 + colbase + c0 + lc2] =
            t[lc2][ln2 + it * 8];
}

// ---------------------------------------------------------------------------
// k3_mfma: Gram partials via MFMA, operands direct from global.
// grid (32 n-chunks of 512, 8 = t*4+h, 4 b), block 256 = 4 waves.
// ---------------------------------------------------------------------------
__global__ __launch_bounds__(256) void k3_mfma(
    const bf16* __restrict__ QT, float* __restrict__ Gpart)
{
    const int chunk = blockIdx.x;
    const int t = blockIdx.y >> 2, h = blockIdx.y & 3;
    const int b = blockIdx.z;
    const int qch = (t == 0 ? 0 : 576) + h * CHD;
    const int kch = (t == 0 ? 192 : 768) + h * CHD;
    const bf16* qp = QT + ((size_t)b * TOT + qch) * NN;
    const bf16* kp = QT + ((size_t)b * TOT + kch) * NN;

    const int tid = threadIdx.x;
    const int wave = tid >> 6, lane = tid & 63;
    const int lm = lane & 15, lq = lane >> 4;
    const int n0 = chunk * 512 + wave * 128;

    float4_ acc[3][3];
    #pragma unroll
    for (int i = 0; i < 3; ++i)
        #pragma unroll
        for (int j = 0; j < 3; ++j)
            acc[i][j] = (float4_){0.f, 0.f, 0.f, 0.f};

    #pragma unroll
    for (int kk = 0; kk < 128; kk += 32) {
        short8 af[3], bfr[3];
        const int ko = n0 + kk + lq * 8;
        #pragma unroll
        for (int i = 0; i < 3; ++i)
            af[i] = *(const short8*)&qp[(size_t)(i * 16 + lm) * NN + ko];
        #pragma unroll
        for (int j = 0; j < 3; ++j)
            bfr[j] = *(const short8*)&kp[(size_t)(j * 16 + lm) * NN + ko];
        #pragma unroll
        for (int i = 0; i < 3; ++i)
            #pragma unroll
            for (int j = 0; j < 3; ++j)
                acc[i][j] = __builtin_amdgcn_mfma_f32_16x16x32_bf16(
                    af[i], bfr[j], acc[i][j], 0, 0, 0);
    }

    __shared__ float sW[4][48 * 49];
    #pragma unroll
    for (int i = 0; i < 3; ++i)
        #pragma unroll
        for (int j = 0; j < 3; ++j)
            #pragma unroll
            for (int r = 0; r < 4; ++r)
                sW[wave][(i * 16 + lq * 4 + r) * 49 + j * 16 + lm] = acc[i][j][r];
    __syncthreads();

    const int gidx = ((t * 4 + b) * 4 + h);
    float* Gp = Gpart + ((size_t)gidx * 32 + chunk) * 2304;
    for (int idx = tid; idx < 2304; idx += 256) {
        const int c = idx / 48, d = idx % 48;
        Gp[idx] = sW[0][c * 49 + d] + sW[1][c * 49 + d]
                + sW[2][c * 49 + d] + sW[3][c * 49 + d];
    }
}

// ---------------------------------------------------------------------------
// kred: G[gidx][2304] = sum over 32 chunks of Gpart[gidx][chunk][2304].
// ---------------------------------------------------------------------------
__global__ __launch_bounds__(256) void kred(
    const float* __restrict__ Gpart, float* __restrict__ G)
{
    const int idx = blockIdx.x * 256 + threadIdx.x;
    if (idx >= 32 * 2304) return;
    const int g = idx / 2304, i = idx % 2304;
    const float* p = Gpart + (size_t)g * 32 * 2304 + i;
    float s = 0.f;
    #pragma unroll
    for (int ch = 0; ch < 32; ++ch) s += p[(size_t)ch * 2304];
    G[(size_t)g * 2304 + i] = s;
}

// ---------------------------------------------------------------------------
// K4: softmax(G * temp / (|q||k|)) then fold proj -> Mb bf16 [b][o][384].
// ---------------------------------------------------------------------------
__global__ __launch_bounds__(256) void k4_softmax_m(
    const float* __restrict__ G, const float* __restrict__ nrmsq,
    const float* __restrict__ proj_w, const float* __restrict__ tq,
    const float* __restrict__ tm, bf16* __restrict__ Mb)
{
    const int h = blockIdx.x, t = blockIdx.y, b = blockIdx.z;
    const float* Gp = G + (((size_t)t * 4 + b) * 4 + h) * 2304;
    __shared__ float sA[48][49];
    const int tid = threadIdx.x;

    if (tid < 48) {
        const int c = tid;
        const int clsq = (t == 0) ? 0 : 2, clsk = (t == 0) ? 1 : 3;
        const float nq =
            fmaxf(sqrtf(fmaxf(nrmsq[(b * 4 + clsq) * 192 + h * 48 + c], 0.f)), 1e-12f);
        const float tmp = (t == 0 ? tq[h] : tm[h]);
        float L[48];
        float mx = -1e30f;
        for (int d = 0; d < 48; ++d) {
            float nk =
                fmaxf(sqrtf(fmaxf(nrmsq[(b * 4 + clsk) * 192 + h * 48 + d], 0.f)), 1e-12f);
            L[d] = Gp[c * 48 + d] * tmp / (nq * nk);
            mx = fmaxf(mx, L[d]);
        }
        float sum = 0.f;
        for (int d = 0; d < 48; ++d) { L[d] = expf(L[d] - mx); sum += L[d]; }
        const float inv = 1.f / sum;
        for (int d = 0; d < 48; ++d) sA[c][d] = L[d] * inv;
    }
    __syncthreads();

    for (int idx = tid; idx < 192 * 48; idx += 256) {
        const int o = idx / 48, d = idx % 48;
        const float* pw = proj_w + o * 384 + t * 192 + h * 48;
        float s = 0.f;
        for (int c = 0; c < 48; ++c) s += pw[c] * sA[c][d];
        Mb[((size_t)b * 192 + o) * 384 + t * 192 + h * 48 + d] = __float2bfloat16(s);
    }
}

// ---------------------------------------------------------------------------
// k5_mfma: out[b][192][16384] = Mb[b][192][384] x Vt[b][16384][384]^T (MFMA).
// ---------------------------------------------------------------------------
__global__ __launch_bounds__(256) void k5_mfma(
    const bf16* __restrict__ Mb, const bf16* __restrict__ Vt,
    float* __restrict__ out)
{
    const int nt0 = blockIdx.x * 128;
    const int mt0 = blockIdx.y * 64;
    const int b   = blockIdx.z;
    const int tid = threadIdx.x;

    __shared__ short sB[128][72];

    const int wave = tid >> 6, lane = tid & 63;
    const int mw = (wave & 1) * 32, nw = (wave >> 1) * 64;
    const int lm = lane & 15, lq = lane >> 4;

    const bf16* Vb = Vt + (size_t)b * NN * 384;
    const bf16* Mp = Mb + (size_t)b * 192 * 384;

    float4_ acc[2][4];
    #pragma unroll
    for (int i = 0; i < 2; ++i)
        #pragma unroll
        for (int j = 0; j < 4; ++j)
            acc[i][j] = (float4_){0.f, 0.f, 0.f, 0.f};

    for (int kc = 0; kc < 384; kc += 64) {
        __syncthreads();
        {
            int r = tid >> 3, c8 = (tid & 7) * 8;
            #pragma unroll
            for (int it = 0; it < 4; ++it, r += 32)
                *(short8*)&sB[r][c8] =
                    *(const short8*)&Vb[(size_t)(nt0 + r) * 384 + kc + c8];
        }
        __syncthreads();
        #pragma unroll
        for (int kk = 0; kk < 64; kk += 32) {
            short8 af[2], bfr[4];
            const int ko = kk + lq * 8;
            #pragma unroll
            for (int i = 0; i < 2; ++i)
                af[i] = *(const short8*)
                    &Mp[(size_t)(mt0 + mw + i * 16 + lm) * 384 + kc + ko];
            #pragma unroll
            for (int j = 0; j < 4; ++j)
                bfr[j] = *(const short8*)&sB[nw + j * 16 + lm][ko];
            #pragma unroll
            for (int i = 0; i < 2; ++i)
                #pragma unroll
                for (int j = 0; j < 4; ++j)
                    acc[i][j] = __builtin_amdgcn_mfma_f32_16x16x32_bf16(
                        af[i], bfr[j], acc[i][j], 0, 0, 0);
        }
    }
    #pragma unroll
    for (int i = 0; i < 2; ++i)
        #pragma unroll
        for (int j = 0; j < 4; ++j) {
            const int n = nt0 + nw + j * 16 + lm;
            #pragma unroll
            for (int r = 0; r < 4; ++r) {
                const int m = mt0 + mw + i * 16 + lq * 4 + r;
                out[((size_t)b * C_ + m) * NN + n] = acc[i][j][r];
            }
        }
}

// ---------------------------------------------------------------------------
extern "C" void kernel_launch(void* const* d_in, const int* in_sizes, int n_in,
                              void* d_out, int out_size, void* d_ws, size_t ws_size,
                              hipStream_t stream)
{
    const float* x     = (const float*)d_in[0];
    const float* xh    = (const float*)d_in[1];
    const float* qkvw  = (const float*)d_in[2];
    const float* qkvdw = (const float*)d_in[3];
    const float* qmw   = (const float*)d_in[4];
    const float* qmdw  = (const float*)d_in[5];
    const float* kvmw  = (const float*)d_in[6];
    const float* kvmdw = (const float*)d_in[7];
    const float* projw = (const float*)d_in[8];
    const float* tq    = (const float*)d_in[9];
    const float* tm    = (const float*)d_in[10];
    float* out = (float*)d_out;

    char* ws = (char*)d_ws;
    size_t off = 0;
    bf16*  QT = (bf16*)(ws + off);  off += (size_t)B_ * TOT * NN * 2;   // 151.0 MB
    bf16*  Y  = (bf16*)(ws + off);                                      // batch-loop only
    bf16*  Vt = (bf16*)(ws + off);  off += (size_t)TOT * NN * 2;        // overlays Y(+Xt)
    bf16*  Xt = (bf16*)(ws + off);  off += (size_t)2 * NN * C_ * 2;
    bf16*  Wb = (bf16*)(ws + off);  off += (size_t)TOT * C_ * 2;
    float* nrm = (float*)(ws + off); off += (size_t)B_ * 4 * 192 * 4;
    float* G   = (float*)(ws + off); off += (size_t)2 * B_ * HEADS * 48 * 48 * 4;
    bf16*  Mb  = (bf16*)(ws + off);  off += (size_t)B_ * 192 * 384 * 2;
    float* Gpart = (float*)(ws + off); off += (size_t)32 * 32 * 2304 * 4;  // 9.4 MB

    hipMemsetAsync(nrm, 0, (size_t)B_ * 4 * 192 * 4, stream);

    kprep_w<<<dim3((TOT * C_ + 255) / 256), 256, 0, stream>>>(qkvw, qmw, kvmw, Wb);

    for (int b = 0; b < B_; ++b) {
        kprep_x<<<dim3(512, 6, 2), 256, 0, stream>>>(x, xh, b, Xt);
        kgemm  <<<dim3(128, 18), 256, 0, stream>>>(Wb, Xt, Y);
        kdw    <<<dim3(1152, 2), 256, 0, stream>>>(Y, qkvdw, qmdw, kvmdw, b, QT, nrm);
    }

    ktv         <<<dim3(512, 6, 8), 256, 0, stream>>>(QT, Vt);
    k3_mfma     <<<dim3(32, 8, B_), 256, 0, stream>>>(QT, Gpart);
    kred        <<<dim3((32 * 2304 + 255) / 256), 256, 0, stream>>>(Gpart, G);
    k4_softmax_m<<<dim3(4, 2, B_), 256, 0, stream>>>(G, nrm, projw, tq, tm, Mb);
    k5_mfma     <<<dim3(128, 3, B_), 256, 0, stream>>>(Mb, Vt, out);
}